// Round 5
// baseline (80.328 us; speedup 1.0000x reference)
//
#include <hip/hip_runtime.h>
#include <math.h>

// Problem constants (fixed by the reference: B=4, N=4096, D=3)
constexpr int B_  = 4;
constexpr int N_  = 4096;
constexpr int NV  = N_ * 3;      // 12288 flattened residual elements per (batch,dir)
constexpr int QPT = 8;           // queries per thread in the NN kernel

// float <-> monotonic uint key (order-preserving for all finite floats)
__device__ inline unsigned f2k(float f) {
    unsigned b = __float_as_uint(f);
    return b ^ ((unsigned)((int)b >> 31) | 0x80000000u);
}
__device__ inline float k2f(unsigned k) {
    unsigned b = (k & 0x80000000u) ? (k ^ 0x80000000u) : ~k;
    return __uint_as_float(b);
}

// ---------------------------------------------------------------------------
// Kernel 1a: partial NN over a candidate chunk, 8 queries per thread.
// grid = (ncch cand chunks, 2 query chunks, 8 pairs), block = 256.
// LDS candidates prescaled {-2bx,-2by,-2bz,|b|^2} -> d2 in 3 FMAs.
// One ds_read_b128 per candidate feeds 8 query updates (LDS amortized 8x).
// Strict '<' keeps the FIRST minimal index (jnp.argmin tie-break).
// ---------------------------------------------------------------------------
__global__ __launch_bounds__(256) void nn_partial_kernel(const float* __restrict__ x,
                                                         const float* __restrict__ y,
                                                         float2* __restrict__ part,
                                                         int ncch) {
    __shared__ float4 s2[1024];             // 16 KB (max chunk size)
    const int cch  = N_ / ncch;
    const int pair = blockIdx.z;
    const int b    = pair >> 1;
    const int dir  = pair & 1;              // 0: S1=x,S2=y ; 1: S1=y,S2=x
    const float* S1 = (dir == 0 ? x : y) + b * NV;
    const float* S2 = (dir == 0 ? y : x) + b * NV;
    const int cbase = blockIdx.x * cch;

    for (int j = threadIdx.x; j < cch; j += 256) {
        float bx = S2[(cbase + j) * 3 + 0];
        float by = S2[(cbase + j) * 3 + 1];
        float bz = S2[(cbase + j) * 3 + 2];
        s2[j] = make_float4(-2.f * bx, -2.f * by, -2.f * bz,
                            bx * bx + by * by + bz * bz);
    }
    __syncthreads();

    // 8 contiguous queries per thread: 24 floats = 6 aligned float4 loads.
    const int q0 = blockIdx.y * 2048 + threadIdx.x * QPT;
    float ax[QPT], ay[QPT], az[QPT];
    {
        const float4* p4 = (const float4*)(S1 + q0 * 3);
        float4 v[6];
        #pragma unroll
        for (int i = 0; i < 6; ++i) v[i] = p4[i];
        const float* f = (const float*)v;
        #pragma unroll
        for (int k = 0; k < QPT; ++k) {
            ax[k] = f[k * 3 + 0]; ay[k] = f[k * 3 + 1]; az[k] = f[k * 3 + 2];
        }
    }

    float best[QPT]; int idx[QPT];
    #pragma unroll
    for (int k = 0; k < QPT; ++k) { best[k] = INFINITY; idx[k] = 0; }

    #pragma unroll 2
    for (int j = 0; j < cch; ++j) {
        float4 c = s2[j];                   // uniform address broadcast
        const int jg = cbase + j;           // SGPR
        #pragma unroll
        for (int k = 0; k < QPT; ++k) {
            // d2 = |b|^2 - 2 a.b  (3 FMAs on prescaled candidate)
            float d2 = fmaf(ax[k], c.x, fmaf(ay[k], c.y, fmaf(az[k], c.z, c.w)));
            if (d2 < best[k]) idx[k] = jg;  // v_cmp + v_cndmask
            best[k] = fminf(d2, best[k]);   // v_min
        }
    }

    float2 o[QPT];
    #pragma unroll
    for (int k = 0; k < QPT; ++k) o[k] = make_float2(best[k], (float)idx[k]);
    float4* op = (float4*)(part + (size_t)(pair * ncch + blockIdx.x) * N_ + q0);
    #pragma unroll
    for (int i = 0; i < QPT / 2; ++i) op[i] = ((const float4*)o)[i];
}

// ---------------------------------------------------------------------------
// Kernel 1b: merge the ncch partials per query (ascending chunk order + strict
// '<' == global first-index argmin), gather S2[idx], write residuals.
// grid = (N/256, 8 pairs), block = 256.
// ---------------------------------------------------------------------------
__global__ __launch_bounds__(256) void nn_merge_kernel(const float* __restrict__ x,
                                                       const float* __restrict__ y,
                                                       const float2* __restrict__ part,
                                                       float* __restrict__ resid,
                                                       int ncch) {
    const int pair = blockIdx.y;
    const int b    = pair >> 1;
    const int dir  = pair & 1;
    const float* S1 = (dir == 0 ? x : y) + b * NV;
    const float* S2 = (dir == 0 ? y : x) + b * NV;
    const int q = blockIdx.x * 256 + threadIdx.x;

    float best = INFINITY;
    int bidx = 0;
    for (int c = 0; c < ncch; ++c) {
        float2 p = part[(size_t)(pair * ncch + c) * N_ + q];
        if (p.x < best) { best = p.x; bidx = (int)p.y; }
    }
    float* outp = resid + pair * NV + q * 3;
    outp[0] = S1[q * 3 + 0] - S2[bidx * 3 + 0];
    outp[1] = S1[q * 3 + 1] - S2[bidx * 3 + 1];
    outp[2] = S1[q * 3 + 2] - S2[bidx * 3 + 2];
}

// ---------------------------------------------------------------------------
// Kernel 2: exact quantile via MSD radix select (4 x 8-bit passes in LDS).
// grid = 32 (pair*4 + quantile_idx), block = 256 (4-wave barriers are cheap).
// ---------------------------------------------------------------------------
__global__ __launch_bounds__(256) void quantile_select_kernel(const float* __restrict__ resid,
                                                              float* __restrict__ qbuf) {
    __shared__ unsigned keys[NV];           // 48 KB
    __shared__ int hist[256];
    __shared__ int s_sel, s_want, s_cnt;
    __shared__ unsigned s_min;

    const int t    = blockIdx.x & 3;        // quantile index
    const int pair = blockIdx.x >> 2;
    const int tid  = threadIdx.x;
    const int lane = tid & 63;

    const float Qs[4] = {0.05f, 0.95f, 0.25f, 0.75f};
    const float pos = Qs[t] * (float)(NV - 1);   // fp32, matches jnp.quantile
    const int   k0  = (int)floorf(pos);
    const float fr  = pos - (float)k0;

    // Vectorized load + key conversion.
    const float4* v4 = (const float4*)(resid + pair * NV);
    for (int i = tid; i < NV / 4; i += 256) {
        float4 v = v4[i];
        uint4 k = make_uint4(f2k(v.x), f2k(v.y), f2k(v.z), f2k(v.w));
        ((uint4*)keys)[i] = k;
    }
    __syncthreads();

    // MSD radix select for the k0-th smallest (0-based).
    unsigned prefix = 0u, pmask = 0u;
    int want = k0;
    for (int shift = 24; shift >= 0; shift -= 8) {
        hist[tid] = 0;
        __syncthreads();
        for (int i = tid; i < NV; i += 256) {
            unsigned k = keys[i];
            if ((k & pmask) == prefix) atomicAdd(&hist[(k >> shift) & 255], 1);
        }
        __syncthreads();
        if (tid < 64) {                     // wave-parallel 256-bin scan
            int c0 = hist[tid * 4 + 0], c1 = hist[tid * 4 + 1];
            int c2 = hist[tid * 4 + 2], c3 = hist[tid * 4 + 3];
            int s = c0 + c1 + c2 + c3;
            int pre = s;
            #pragma unroll
            for (int off = 1; off < 64; off <<= 1) {
                int u = __shfl_up(pre, off);
                if (tid >= off) pre += u;
            }
            int excl = pre - s;             // count in lanes before this one
            bool hit = (want >= excl) && (want < excl + s);
            unsigned long long m = __ballot(hit);
            int hl = (int)(__ffsll((unsigned long long)m) - 1);
            if (tid == hl) {
                int w = want - excl;
                int sel;
                if      (w < c0)           { sel = tid * 4 + 0; }
                else if (w < c0 + c1)      { sel = tid * 4 + 1; w -= c0; }
                else if (w < c0 + c1 + c2) { sel = tid * 4 + 2; w -= c0 + c1; }
                else                       { sel = tid * 4 + 3; w -= c0 + c1 + c2; }
                s_sel = sel; s_want = w;
            }
        }
        __syncthreads();
        prefix |= ((unsigned)s_sel) << shift;
        pmask  |= (0xFFu << shift);
        want = s_want;
        __syncthreads();
    }
    const unsigned key0 = prefix;           // exact k0-th smallest key
    const float v0 = k2f(key0);

    // (k0+1)-th order stat: duplicate-aware, wave-reduced atomics.
    if (tid == 0) { s_cnt = 0; s_min = 0xFFFFFFFFu; }
    __syncthreads();
    int loc = 0; unsigned locmin = 0xFFFFFFFFu;
    for (int i = tid; i < NV; i += 256) {
        unsigned k = keys[i];
        if (k <= key0) loc++;
        else if (k < locmin) locmin = k;
    }
    for (int off = 32; off > 0; off >>= 1) {
        loc += __shfl_down(loc, off);
        unsigned m2 = __shfl_down(locmin, off);
        locmin = (m2 < locmin) ? m2 : locmin;
    }
    if (lane == 0) { atomicAdd(&s_cnt, loc); atomicMin(&s_min, locmin); }
    __syncthreads();
    if (tid == 0) {
        float v1 = (s_cnt >= k0 + 2) ? v0 : k2f(s_min);
        qbuf[pair * 4 + t] = v0 + fr * (v1 - v0);
    }
}

// ---------------------------------------------------------------------------
// Kernel 3: masked two-pass mean/std per pair. grid = 8, block = 256.
// ---------------------------------------------------------------------------
__global__ __launch_bounds__(256) void masked_stats_kernel(const float* __restrict__ resid,
                                                           const float* __restrict__ qbuf,
                                                           float* __restrict__ stats) {
    __shared__ float red[16];
    __shared__ float sh[8];
    const int pair = blockIdx.x;
    const int tid  = threadIdx.x;
    const int wid = tid >> 6, lane = tid & 63;
    const float4* v4 = (const float4*)(resid + pair * NV);
    const float q0 = qbuf[pair * 4 + 0], q1 = qbuf[pair * 4 + 1];
    const float q2 = qbuf[pair * 4 + 2], q3 = qbuf[pair * 4 + 3];

    // Pass 1: masked counts and sums (vectorized loads).
    float cb = 0.f, sb = 0.f, ce = 0.f, se = 0.f;
    for (int i = tid; i < NV / 4; i += 256) {
        float4 v = v4[i];
        float vals[4] = {v.x, v.y, v.z, v.w};
        #pragma unroll
        for (int u = 0; u < 4; ++u) {
            float val = vals[u];
            if ((val < q0) || (val > q1)) { cb += 1.f; sb += val; }
            if ((val > q2) && (val < q3)) { ce += 1.f; se += val; }
        }
    }
    for (int off = 32; off > 0; off >>= 1) {
        cb += __shfl_down(cb, off);
        sb += __shfl_down(sb, off);
        ce += __shfl_down(ce, off);
        se += __shfl_down(se, off);
    }
    if (lane == 0) {
        red[wid * 4 + 0] = cb; red[wid * 4 + 1] = sb;
        red[wid * 4 + 2] = ce; red[wid * 4 + 3] = se;
    }
    __syncthreads();
    if (tid == 0) {
        float tcb = 0.f, tsb = 0.f, tce = 0.f, tse = 0.f;
        for (int w = 0; w < 4; ++w) {
            tcb += red[w * 4 + 0]; tsb += red[w * 4 + 1];
            tce += red[w * 4 + 2]; tse += red[w * 4 + 3];
        }
        sh[0] = tsb / tcb;                  // mean_begin
        sh[1] = tse / tce;                  // mean_end
        sh[2] = tcb;                        // n_begin
        sh[3] = tce;                        // n_end
    }
    __syncthreads();
    const float mean_b = sh[0], mean_e = sh[1];
    const float nb = sh[2], ne = sh[3];

    // Pass 2: masked sum of squared deviations.
    float vb = 0.f, ve = 0.f;
    for (int i = tid; i < NV / 4; i += 256) {
        float4 v = v4[i];
        float vals[4] = {v.x, v.y, v.z, v.w};
        #pragma unroll
        for (int u = 0; u < 4; ++u) {
            float val = vals[u];
            if ((val < q0) || (val > q1)) { float d = val - mean_b; vb += d * d; }
            if ((val > q2) && (val < q3)) { float d = val - mean_e; ve += d * d; }
        }
    }
    for (int off = 32; off > 0; off >>= 1) {
        vb += __shfl_down(vb, off);
        ve += __shfl_down(ve, off);
    }
    __syncthreads();
    if (lane == 0) { red[wid * 2 + 0] = vb; red[wid * 2 + 1] = ve; }
    __syncthreads();
    if (tid == 0) {
        float tvb = 0.f, tve = 0.f;
        for (int w = 0; w < 4; ++w) { tvb += red[w * 2 + 0]; tve += red[w * 2 + 1]; }
        stats[pair * 2 + 0] = sqrtf(tvb / (nb - 1.f));   // unbiased std, begin
        stats[pair * 2 + 1] = sqrtf(tve / (ne - 1.f));   // unbiased std, end
    }
}

// ---------------------------------------------------------------------------
// Kernel 4: per-batch max over directions, mean over batches.
// ---------------------------------------------------------------------------
__global__ void final_kernel(const float* __restrict__ stats, float* __restrict__ out) {
    if (threadIdx.x == 0 && blockIdx.x == 0) {
        float sb = 0.f, se = 0.f;
        for (int b = 0; b < B_; ++b) {
            float b1 = stats[(b * 2 + 0) * 2 + 0];
            float b2 = stats[(b * 2 + 1) * 2 + 0];
            float e1 = stats[(b * 2 + 0) * 2 + 1];
            float e2 = stats[(b * 2 + 1) * 2 + 1];
            sb += fmaxf(b1, b2);
            se += fmaxf(e1, e2);
        }
        out[0] = sb / (float)B_;
        out[1] = se / (float)B_;
    }
}

extern "C" void kernel_launch(void* const* d_in, const int* in_sizes, int n_in,
                              void* d_out, int out_size, void* d_ws, size_t ws_size,
                              hipStream_t stream) {
    const float* x = (const float*)d_in[0];
    const float* y = (const float*)d_in[1];
    float* out = (float*)d_out;

    // Fixed-head workspace layout; candidate-chunk count adapts to ws_size.
    float*  resid = (float*)d_ws;                        // 8*NV floats = 384 KB
    float*  qbuf  = resid + 8 * NV;                      // 32 floats
    float*  stats = qbuf + 32;                           // 16 floats
    float2* part  = (float2*)(stats + 16 + 16);          // rest of ws

    const size_t head = (size_t)(8 * NV + 64) * sizeof(float);
    int ncch = 4;                                        // 1.4 MB proven floor
    for (int c = 32; c >= 4; c >>= 1) {
        size_t need = head + (size_t)8 * c * N_ * sizeof(float2);
        if (ws_size >= need) { ncch = c; break; }
    }

    nn_partial_kernel<<<dim3(ncch, 2, 8), 256, 0, stream>>>(x, y, part, ncch);
    nn_merge_kernel<<<dim3(N_ / 256, 8), 256, 0, stream>>>(x, y, part, resid, ncch);
    quantile_select_kernel<<<32, 256, 0, stream>>>(resid, qbuf);
    masked_stats_kernel<<<8, 256, 0, stream>>>(resid, qbuf, stats);
    final_kernel<<<1, 64, 0, stream>>>(stats, out);
}